// Round 11
// baseline (262.053 us; speedup 1.0000x reference)
//
#include <hip/hip_runtime.h>
#include <hip/hip_bf16.h>

#define B_ 2
#define C_ 512
#define HW_ 4096
#define K_ 512
#define EPS_ 1e-6f
#define SCALE_ 0.04419417382415922f   // 512^-0.5
#define NEG_INF_ (-1e30f)

typedef __attribute__((ext_vector_type(8))) __bf16 bf16x8;
typedef __attribute__((ext_vector_type(4))) float f32x4;
typedef __attribute__((ext_vector_type(16))) float f32x16;

__device__ __forceinline__ unsigned short f2bf(float f) {
  union { float f; unsigned u; } v; v.f = f;
  unsigned r = v.u + 0x7fffu + ((v.u >> 16) & 1u);
  return (unsigned short)(r >> 16);
}
__device__ __forceinline__ float bf2f(unsigned short h) {
  union { unsigned u; float f; } v; v.u = ((unsigned)h) << 16;
  return v.f;
}

// direct global->LDS DMA, 16B per lane. LDS dst = wave-uniform base + lane*16.
__device__ __forceinline__ void gld_lds16(const unsigned short* g, unsigned short* l) {
  __builtin_amdgcn_global_load_lds((const __attribute__((address_space(1))) void*)g,
                                   (__attribute__((address_space(3))) void*)l, 16, 0, 0);
}

// ------- sum_t: ONE pass over x. transpose/cast x(b,c,n) f32 -> t_raw(b,n,c) bf16
// AND emit per-block GN partial sums (GN itself is folded into weights by wprep).
// pstats[((b*8+cb)*4+g)*64 + nblk] = sum; +4096 = sumsq.
__global__ void sum_t(const float* __restrict__ x, float* __restrict__ pstats,
                      unsigned short* __restrict__ tb) {
  __shared__ float lds[64 * 69];
  __shared__ float ps[64], ps2[64];
  int n0 = blockIdx.x * 64, c0 = blockIdx.y * 64, b = blockIdx.z;
  int t = threadIdx.x;
  {
    int cl = t >> 2, ch = t & 3;
    const float* xr = x + ((size_t)(b * C_ + c0 + cl)) * HW_ + n0 + ch * 16;
    float s = 0.f, s2 = 0.f;
    #pragma unroll
    for (int i = 0; i < 4; ++i) {
      float4 v = *reinterpret_cast<const float4*>(xr + i * 4);
      int nl = ch * 16 + i * 4;
      lds[cl * 69 + nl + 0] = v.x;
      lds[cl * 69 + nl + 1] = v.y;
      lds[cl * 69 + nl + 2] = v.z;
      lds[cl * 69 + nl + 3] = v.w;
      s  += v.x + v.y + v.z + v.w;
      s2 += v.x * v.x + v.y * v.y + v.z * v.z + v.w * v.w;
    }
    // combine the 4 ch-threads sharing one c (lane bits 0,1)
    s += __shfl_xor(s, 1); s2 += __shfl_xor(s2, 1);
    s += __shfl_xor(s, 2); s2 += __shfl_xor(s2, 2);
    if (ch == 0) { ps[cl] = s; ps2[cl] = s2; }
  }
  __syncthreads();
  if (t < 4) {   // per-group (16 c) partials
    float a = 0.f, a2 = 0.f;
    #pragma unroll
    for (int k = 0; k < 16; ++k) { a += ps[t * 16 + k]; a2 += ps2[t * 16 + k]; }
    int idx = ((b * 8 + blockIdx.y) * 4 + t) * 64 + blockIdx.x;
    pstats[idx] = a; pstats[4096 + idx] = a2;
  }
  {
    int nl = t >> 2, cw = t & 3;
    unsigned short* orow = tb + ((size_t)(b * HW_ + n0 + nl)) * C_ + c0 + cw * 16;
    #pragma unroll
    for (int i = 0; i < 4; ++i) {
      ushort4 o4;
      o4.x = f2bf(lds[(cw * 16 + i * 4 + 0) * 69 + nl]);
      o4.y = f2bf(lds[(cw * 16 + i * 4 + 1) * 69 + nl]);
      o4.z = f2bf(lds[(cw * 16 + i * 4 + 2) * 69 + nl]);
      o4.w = f2bf(lds[(cw * 16 + i * 4 + 3) * 69 + nl]);
      *reinterpret_cast<ushort4*>(orow + i * 4) = o4;
    }
  }
}

// ------- wprep: finalize stats; emit per-batch GN-scaled weights w' = w .* ga (bf16),
// folded biases bias' = b_w + w . be, and the plain wp cast (slot 6).
// grid (8, 4, 2): x = o-block(64), y = which (0=q,1=k,2=v,3=wp), z = b.
__global__ void wprep(const float* __restrict__ pstats,
                      const float* __restrict__ gamma, const float* __restrict__ beta,
                      const float* __restrict__ wq, const float* __restrict__ wk,
                      const float* __restrict__ wv, const float* __restrict__ wp,
                      const float* __restrict__ bq, const float* __restrict__ bk,
                      const float* __restrict__ bv,
                      unsigned short* __restrict__ wqkvb, float* __restrict__ biasb) {
  int which = blockIdx.y, b = blockIdx.z;
  if (which == 3 && b == 1) return;
  int t = threadIdx.x;
  __shared__ float sg[32], sg2[32], ga[512], be[512];
  if (which < 3) {
    if (t < 64) {
      int g = t & 31, hf = t >> 5;
      const float* base = pstats + hf * 4096 + (size_t)(b * 32 + g) * 64;
      float a = 0.f;
      for (int k = 0; k < 64; ++k) a += base[k];
      if (hf) sg2[g] = a; else sg[g] = a;
    }
    __syncthreads();
    for (int c = t; c < 512; c += 256) {
      int g = c >> 4;
      float mean = sg[g] * (1.f / 65536.f);
      float var = sg2[g] * (1.f / 65536.f) - mean * mean;
      float rstd = rsqrtf(var + EPS_);
      float gav = gamma[c] * rstd;
      ga[c] = gav; be[c] = beta[c] - mean * gav;
    }
    __syncthreads();
  }
  const float* w = which == 0 ? wq : which == 1 ? wk : which == 2 ? wv : wp;
  int ol = t >> 2, ch = t & 3;
  int o = blockIdx.x * 64 + ol;
  const float* wr = w + (size_t)o * 512 + ch * 128;
  unsigned short* wo = wqkvb + (size_t)(which < 3 ? (which * 2 + b) : 6) * 262144
                     + (size_t)o * 512 + ch * 128;
  float pd = 0.f;
  #pragma unroll 8
  for (int i = 0; i < 32; ++i) {
    float4 v = *reinterpret_cast<const float4*>(wr + i * 4);
    int c = ch * 128 + i * 4;
    ushort4 o4;
    if (which < 3) {
      pd += be[c] * v.x + be[c + 1] * v.y + be[c + 2] * v.z + be[c + 3] * v.w;
      o4.x = f2bf(v.x * ga[c]);     o4.y = f2bf(v.y * ga[c + 1]);
      o4.z = f2bf(v.z * ga[c + 2]); o4.w = f2bf(v.w * ga[c + 3]);
    } else {
      o4.x = f2bf(v.x); o4.y = f2bf(v.y); o4.z = f2bf(v.z); o4.w = f2bf(v.w);
    }
    *reinterpret_cast<ushort4*>(wo + i * 4) = o4;
  }
  if (which < 3) {
    pd += __shfl_xor(pd, 1);
    pd += __shfl_xor(pd, 2);
    if (ch == 0) {
      const float* b0 = which == 0 ? bq : which == 1 ? bk : bv;
      biasb[(which * 2 + b) * 512 + o] = b0[o] + pd;
    }
  }
}

// ---------------- fused Q/K/V^T projections, one launch (XCD-grouped) ----------------
// per-batch scaled weights from wprep; folded biases from biasb.
__global__ __launch_bounds__(256, 2) void gemm_qkv(
    const unsigned short* __restrict__ tb, const unsigned short* __restrict__ wqkvb,
    const float* __restrict__ biasb,
    unsigned short* __restrict__ qb, unsigned short* __restrict__ kb,
    unsigned short* __restrict__ vTb) {
  __shared__ unsigned short Al[2][128 * 64];
  __shared__ unsigned short Bl[2][128 * 64];
  // bijective remap of 768 blocks: xcd = f&7 fixed; i>>2 selects (y,z) combo, i&3 the x
  int f = blockIdx.x + 4 * (blockIdx.y + 32 * blockIdx.z);
  int xcd = f & 7, i = f >> 3;
  int bx = i & 3;
  int g = xcd * 24 + (i >> 2);     // 0..191
  int bz = g >> 5, by = g & 31;
  int which = bz >> 1, b = bz & 1;
  const unsigned short* Ab = (which < 2) ? (tb + (size_t)b * HW_ * K_)
                                         : (wqkvb + (size_t)(4 + b) * 262144);
  const unsigned short* Bb = (which < 2) ? (wqkvb + (size_t)(which * 2 + b) * 262144)
                                         : (tb + (size_t)b * HW_ * K_);
  int m0 = (which < 2) ? by * 128 : bx * 128;
  int n0 = (which < 2) ? bx * 128 : by * 128;
  int N = (which < 2) ? 512 : HW_;
  unsigned short* Cb = (which == 0) ? (qb + (size_t)b * HW_ * K_)
                     : (which == 1) ? (kb + (size_t)b * HW_ * K_)
                                    : (vTb + (size_t)b * C_ * HW_);
  const float* bias = biasb + (which * 2 + b) * 512;
  int t = threadIdx.x, lane = t & 63, w = t >> 6;
  int l15 = lane & 15, quad = lane >> 4;
  int mw = (w & 1) * 64, nw = (w >> 1) * 64;
  int sr8 = lane >> 3, sb = lane & 7;
  f32x4 acc[4][4] = {};

  #define G_STAGE(KC) do {                                                          \
    int pb = (KC) & 1;                                                              \
    _Pragma("unroll")                                                               \
    for (int q = 0; q < 4; ++q) {                                                   \
      int row = w * 32 + q * 8 + sr8;                                               \
      int gb = sb ^ (row & 7);                                                      \
      gld_lds16(Ab + (size_t)(m0 + row) * K_ + (KC) * 64 + gb * 8, &Al[pb][(w * 32 + q * 8) * 64]); \
      gld_lds16(Bb + (size_t)(n0 + row) * K_ + (KC) * 64 + gb * 8, &Bl[pb][(w * 32 + q * 8) * 64]); \
    }                                                                               \
  } while (0)

  G_STAGE(0);
  __syncthreads();
  for (int kc = 0; kc < 8; ++kc) {
    if (kc < 7) G_STAGE(kc + 1);
    const unsigned short* Ac = Al[kc & 1];
    const unsigned short* Bc = Bl[kc & 1];
    #pragma unroll
    for (int kk = 0; kk < 2; ++kk) {
      bf16x8 af[4];
      #pragma unroll
      for (int mt = 0; mt < 4; ++mt)
        af[mt] = *reinterpret_cast<const bf16x8*>(
            &Ac[(mw + mt * 16 + l15) * 64 + (((kk * 4 + quad) ^ (l15 & 7)) << 3)]);
      #pragma unroll
      for (int nt = 0; nt < 4; ++nt) {
        bf16x8 bfr = *reinterpret_cast<const bf16x8*>(
            &Bc[(nw + nt * 16 + l15) * 64 + (((kk * 4 + quad) ^ (l15 & 7)) << 3)]);
        #pragma unroll
        for (int mt = 0; mt < 4; ++mt)
          acc[mt][nt] = __builtin_amdgcn_mfma_f32_16x16x32_bf16(af[mt], bfr, acc[mt][nt], 0, 0, 0);
      }
    }
    __syncthreads();
  }
  #undef G_STAGE
  #pragma unroll
  for (int mt = 0; mt < 4; ++mt)
    #pragma unroll
    for (int nt = 0; nt < 4; ++nt)
      #pragma unroll
      for (int rr = 0; rr < 4; ++rr) {
        int row = m0 + mw + mt * 16 + quad * 4 + rr;
        int col = n0 + nw + nt * 16 + l15;
        float v = acc[mt][nt][rr] + ((which < 2) ? bias[col] : bias[row]);
        Cb[(size_t)row * N + col] = f2bf(v);
      }
}

// ---------------- final projection + residual, with fused opart merge ----------------
// 128x64 tiles -> 512 blocks -> 2 blocks/CU co-resident (r16-verified).
__global__ __launch_bounds__(256, 2) void gemm_fin(
    const unsigned short* __restrict__ A,            // wpb 512x512 bf16 (slot 6)
    const unsigned short* __restrict__ opart,        // 4 parts (jh*2+z)
    const float* __restrict__ mpart, const float* __restrict__ lpart,
    const float* __restrict__ bias, const float* __restrict__ resid,
    float* __restrict__ out) {
  __shared__ unsigned short Al[2][128 * 64];
  __shared__ unsigned short Bl[2][64 * 68];    // padded: row stride 68 shorts
  int z = blockIdx.z;
  int n0 = blockIdx.x * 64, m0 = blockIdx.y * 128;
  int t = threadIdx.x, lane = t & 63, w = t >> 6;
  int l15 = lane & 15, quad = lane >> 4;
  int mw = (w & 1) * 64, nw = (w >> 1) * 32;   // 2 m-waves(64) x 2 n-waves(32)
  int sr8 = lane >> 3, sb = lane & 7;
  f32x4 acc[4][2] = {};

  float w0[2], w1[2];
  int nrow[2];
  #pragma unroll
  for (int q = 0; q < 2; ++q) {
    int n = n0 + w * 16 + q * 8 + sr8;
    nrow[q] = n;
    float ma = mpart[(size_t)z * HW_ + n], mb = mpart[(size_t)(2 + z) * HW_ + n];
    float la = lpart[(size_t)z * HW_ + n], lb = lpart[(size_t)(2 + z) * HW_ + n];
    float M = fmaxf(ma, mb);
    float ea = __expf(ma - M), eb = __expf(mb - M);
    float iv = 1.f / (la * ea + lb * eb);
    w0[q] = ea * iv; w1[q] = eb * iv;
  }
  const unsigned short* p0 = opart + (size_t)z * HW_ * 512;
  const unsigned short* p1 = opart + (size_t)(2 + z) * HW_ * 512;

  #define STAGE_A(KC) do {                                                          \
    int pb = (KC) & 1;                                                              \
    _Pragma("unroll")                                                               \
    for (int q = 0; q < 4; ++q) {                                                   \
      int row = w * 32 + q * 8 + sr8;                                               \
      int gb = sb ^ (row & 7);                                                      \
      gld_lds16(A + (size_t)(m0 + row) * K_ + (KC) * 64 + gb * 8, &Al[pb][(w * 32 + q * 8) * 64]); \
    }                                                                               \
  } while (0)

  #define STAGE_B(KC) do {                                                          \
    int pb = (KC) & 1;                                                              \
    _Pragma("unroll")                                                               \
    for (int q = 0; q < 2; ++q) {                                                   \
      int row = w * 16 + q * 8 + sr8;                                               \
      size_t goff = (size_t)nrow[q] * 512 + (KC) * 64 + sb * 8;                     \
      uint4 u0 = *reinterpret_cast<const uint4*>(p0 + goff);                        \
      uint4 u1 = *reinterpret_cast<const uint4*>(p1 + goff);                        \
      uint4 o4;                                                                     \
      unsigned* a0 = reinterpret_cast<unsigned*>(&u0);                              \
      unsigned* a1 = reinterpret_cast<unsigned*>(&u1);                              \
      unsigned* od = reinterpret_cast<unsigned*>(&o4);                              \
      _Pragma("unroll")                                                             \
      for (int j = 0; j < 4; ++j) {                                                 \
        float lo = bf2f((unsigned short)(a0[j] & 0xffffu)) * w0[q]                  \
                 + bf2f((unsigned short)(a1[j] & 0xffffu)) * w1[q];                 \
        float hi = bf2f((unsigned short)(a0[j] >> 16)) * w0[q]                      \
                 + bf2f((unsigned short)(a1[j] >> 16)) * w1[q];                     \
        od[j] = (unsigned)f2bf(lo) | ((unsigned)f2bf(hi) << 16);                    \
      }                                                                             \
      *reinterpret_cast<uint4*>(&Bl[pb][row * 68 + sb * 8]) = o4;                   \
    }                                                                               \
  } while (0)

  STAGE_A(0);
  STAGE_B(0);
  __syncthreads();
  for (int kc = 0; kc < 8; ++kc) {
    if (kc < 7) { STAGE_A(kc + 1); STAGE_B(kc + 1); }
    const unsigned short* Ac = Al[kc & 1];
    const unsigned short* Bc = Bl[kc & 1];
    #pragma unroll
    for (int kk = 0; kk < 2; ++kk) {
      bf16x8 af[4];
      #pragma unroll
      for (int mt = 0; mt < 4; ++mt)
        af[mt] = *reinterpret_cast<const bf16x8*>(
            &Ac[(mw + mt * 16 + l15) * 64 + (((kk * 4 + quad) ^ (l15 & 7)) << 3)]);
      #pragma unroll
      for (int nt = 0; nt < 2; ++nt) {
        bf16x8 bfr = *reinterpret_cast<const bf16x8*>(
            &Bc[(nw + nt * 16 + l15) * 68 + ((kk * 4 + quad) << 3)]);
        #pragma unroll
        for (int mt = 0; mt < 4; ++mt)
          acc[mt][nt] = __builtin_amdgcn_mfma_f32_16x16x32_bf16(af[mt], bfr, acc[mt][nt], 0, 0, 0);
      }
    }
    __syncthreads();
  }
  #undef STAGE_A
  #undef STAGE_B
  #pragma unroll
  for (int mt = 0; mt < 4; ++mt)
    #pragma unroll
    for (int nt = 0; nt < 2; ++nt)
      #pragma unroll
      for (int rr = 0; rr < 4; ++rr) {
        int row = m0 + mw + mt * 16 + quad * 4 + rr;
        int col = n0 + nw + nt * 16 + l15;
        size_t idx = (size_t)z * (C_ * HW_) + (size_t)row * HW_ + col;
        out[idx] = acc[mt][nt][rr] + bias[row] + resid[idx];
      }
}

// ------- flash attention r17 (verified 132 us): phase-PAIRED, 2 chunks per barrier,
// 4 rotating 32KB buffers; 11 barriers/it; Pl single 128-col half rewritten mid-PV.
__global__ __launch_bounds__(512, 2) void attn(
    const unsigned short* __restrict__ qg, const unsigned short* __restrict__ kg,
    const unsigned short* __restrict__ vg,  // vT: (b, c, n)
    unsigned short* __restrict__ opart, float* __restrict__ mpart, float* __restrict__ lpart) {
  __shared__ unsigned short KVb[4 * 16384];   // 4 x 32KB rotating chunk buffers
  __shared__ unsigned short Pl[64 * 136];     // one 128-j half + pad, 17408 B
  __shared__ float sm_m[64], sm_l[64], sm_alpha[64], sm_red[128];
  int qt = blockIdx.x, jh = blockIdx.y, b = blockIdx.z;
  int t = threadIdx.x, lane = t & 63, w = t >> 6;
  int l15 = lane & 15, quad = lane >> 4;
  int l31 = lane & 31, hl = lane >> 5;
  int rw = w & 3, cw = w >> 2;      // S phase: 4 row-groups(16) x 2 col-halves
  int rw2 = w & 1, dg = w >> 1;     // PV phase: 2 row-groups(32) x 4 d-slots
  int m0 = qt * 64;
  if (t < 64) { sm_m[t] = NEG_INF_; sm_l[t] = 0.f; }

  // staging geometry: thread stages 4 x 16B; wave w covers 1KB blocks w*4+q (4 rows each)
  int st_r[4], st_kb[4];
  #pragma unroll
  for (int q = 0; q < 4; ++q) {
    int blk = w * 4 + q;
    st_r[q] = blk * 4 + (lane >> 4);          // row 0..127 within chunk
    st_kb[q] = (lane & 15) ^ (st_r[q] & 7);   // logical 16B block (col/8)
  }

  #define STAGE_K(JC, KC, J0, BUF) do {                                             \
    const unsigned short* gb = kg + ((size_t)(b * HW_ + (J0) + (JC) * 128)) * K_ + (KC) * 128; \
    unsigned short* lb = KVb + ((BUF) << 14);                                       \
    _Pragma("unroll")                                                               \
    for (int q = 0; q < 4; ++q)                                                     \
      gld_lds16(gb + (size_t)st_r[q] * K_ + st_kb[q] * 8, lb + (w * 4 + q) * 512);  \
  } while (0)

  #define STAGE_V(DC, JC, J0, BUF) do {                                             \
    const unsigned short* gb = vg + ((size_t)(b * K_ + (DC) * 128)) * HW_ + (J0) + (JC) * 128; \
    unsigned short* lb = KVb + ((BUF) << 14);                                       \
    _Pragma("unroll")                                                               \
    for (int q = 0; q < 4; ++q)                                                     \
      gld_lds16(gb + (size_t)st_r[q] * HW_ + st_kb[q] * 8, lb + (w * 4 + q) * 512); \
  } while (0)

  bf16x8 qa[16];
  {
    const unsigned short* qrow = qg + ((size_t)(b * HW_ + m0 + rw * 16 + l15)) * K_ + quad * 8;
    #pragma unroll
    for (int kk = 0; kk < 16; ++kk)
      qa[kk] = *reinterpret_cast<const bf16x8*>(qrow + kk * 32);
  }
  f32x16 acc_o[4] = {};    // [dc]: d = dc*128 + dg*32 + l31

  int j0 = jh * 2048;
  STAGE_K(0, 0, j0, 0);    // S chunk 0 -> buf 0
  STAGE_K(0, 1, j0, 1);    // S chunk 1 -> buf 1
  __syncthreads();         // drains chunks 0,1; publishes sm init

  for (int it = 0; it < 8; ++it, j0 += 256) {
    f32x4 acc_s[8] = {};
    // ===== S: 8 chunks (jc=c>>2, kc=c&3), chunk c in buf c&3; barrier at odd c =====
    #pragma unroll
    for (int c = 0; c < 8; ++c) {
      if ((c & 1) == 0) {
        if (c < 6) {
          STAGE_K((c + 2) >> 2, (c + 2) & 3, j0, (c + 2) & 3);
          STAGE_K((c + 3) >> 2, (c + 3) & 3, j0, (c + 3) & 3);
        } else {           // c==6: stage PV chunks 0,1 (V dc=0,1 jc=0) -> bufs 0,1
          STAGE_V(0, 0, j0, 0);
          STAGE_V(1, 0, j0, 1);
        }
      }
      const unsigned short* bufc = KVb + ((c & 3) << 14);
      int jc = c >> 2, kc = c & 3;
      __builtin_amdgcn_s_setprio(1);
      #pragma unroll
      for (int kk = 0; kk < 4; ++kk)
        #pragma unroll
        for (int ct = 0; ct < 4; ++ct) {
          int jr = cw * 64 + ct * 16 + l15;
          bf16x8 bfr = *reinterpret_cast<const bf16x8*>(
              &bufc[jr * 128 + (((kk * 4 + quad) ^ (l15 & 7)) << 3)]);
          acc_s[jc * 4 + ct] = __builtin_amdgcn_mfma_f32_16x16x32_bf16(qa[kc * 4 + kk], bfr, acc_s[jc * 4 + ct], 0, 0, 0);
        }
      __builtin_amdgcn_s_setprio(0);
      if (c & 1) __syncthreads();
    }
    // ===== softmax =====
    float mx[4];
    #pragma unroll
    for (int rr = 0; rr < 4; ++rr) {
      float m = NEG_INF_;
      #pragma unroll
      for (int s = 0; s < 8; ++s) {
        acc_s[s][rr] *= SCALE_;
        m = fmaxf(m, acc_s[s][rr]);
      }
      mx[rr] = m;
    }
    #pragma unroll
    for (int off = 1; off < 16; off <<= 1)
      #pragma unroll
      for (int rr = 0; rr < 4; ++rr)
        mx[rr] = fmaxf(mx[rr], __shfl_xor(mx[rr], off));
    if (l15 == 0)
      #pragma unroll
      for (int rr = 0; rr < 4; ++rr)
        sm_red[cw * 64 + rw * 16 + quad * 4 + rr] = mx[rr];
    __syncthreads();
    if (t < 64) {
      float mnew = fmaxf(sm_m[t], fmaxf(sm_red[t], sm_red[64 + t]));
      sm_alpha[t] = __expf(sm_m[t] - mnew);
      sm_m[t] = mnew;
    }
    __syncthreads();
    float sum[4] = {0.f, 0.f, 0.f, 0.f};
    #pragma unroll
    for (int s = 0; s < 8; ++s)
      #pragma unroll
      for (int rr = 0; rr < 4; ++rr) {
        int rowl = rw * 16 + quad * 4 + rr;
        float p = __expf(acc_s[s][rr] - sm_m[rowl]);
        sum[rr] += p;
        if (s < 4)   // jc=0 half only; jc=1 rewritten mid-PV from acc_s[4..7]
          Pl[rowl * 136 + cw * 64 + (s & 3) * 16 + l15] = f2bf(p);
      }
    #pragma unroll
    for (int off = 1; off < 16; off <<= 1)
      #pragma unroll
      for (int rr = 0; rr < 4; ++rr)
        sum[rr] += __shfl_xor(sum[rr], off);
    if (l15 == 0)
      #pragma unroll
      for (int rr = 0; rr < 4; ++rr)
        sm_red[cw * 64 + rw * 16 + quad * 4 + rr] = sum[rr];
    __syncthreads();
    if (t < 64)
      sm_l[t] = sm_l[t] * sm_alpha[t] + sm_red[t] + sm_red[64 + t];
    // rescale O by alpha (32x32 C/D row mapping)
    #pragma unroll
    for (int r16 = 0; r16 < 16; ++r16) {
      int row = rw2 * 32 + (r16 & 3) + 8 * (r16 >> 2) + 4 * hl;
      float a = sm_alpha[row];
      #pragma unroll
      for (int dc = 0; dc < 4; ++dc)
        acc_o[dc][r16] *= a;
    }
    // ===== PV: 8 chunks (jc=c>>2, dc=c&3), global 8+c -> buf c&3; barrier at odd c =====
    bf16x8 pa_r[8];
    #pragma unroll
    for (int c = 0; c < 8; ++c) {
      if (c == 2) {
        // rewrite Pl with jc=1 half (jc0 reads done: pa_r loaded at c=0, barrier c=1;
        // reads of this data at c=4, after barrier c=3)
        #pragma unroll
        for (int s = 4; s < 8; ++s)
          #pragma unroll
          for (int rr = 0; rr < 4; ++rr) {
            int rowl = rw * 16 + quad * 4 + rr;
            Pl[rowl * 136 + cw * 64 + (s & 3) * 16 + l15] =
                f2bf(__expf(acc_s[s][rr] - sm_m[rowl]));
          }
      }
      if ((c & 3) == 0) {
        #pragma unroll
        for (int ksx = 0; ksx < 8; ++ksx)
          pa_r[ksx] = *reinterpret_cast<const bf16x8*>(
              &Pl[(rw2 * 32 + l31) * 136 + ksx * 16 + hl * 8]);
      }
      if ((c & 1) == 0) {
        if (c < 6) {
          STAGE_V((c + 2) & 3, (c + 2) >> 2, j0, (c + 2) & 3);
          STAGE_V((c + 3) & 3, (c + 3) >> 2, j0, (c + 3) & 3);
        } else if (it < 7) {   // c==6: stage next-it S chunks 0,1 -> bufs 0,1
          STAGE_K(0, 0, j0 + 256, 0);
          STAGE_K(0, 1, j0 + 256, 1);
        }
      }
      const unsigned short* bufc = KVb + ((c & 3) << 14);
      int dc = c & 3;
      __builtin_amdgcn_s_setprio(1);
      #pragma unroll
      for (int ksx = 0; ksx < 8; ++ksx) {
        bf16x8 vb = *reinterpret_cast<const bf16x8*>(
            &bufc[(dg * 32 + l31) * 128 + (((ksx * 2 + hl) ^ (l31 & 7)) << 3)]);
        acc_o[dc] = __builtin_amdgcn_mfma_f32_32x32x16_bf16(pa_r[ksx], vb, acc_o[dc], 0, 0, 0);
      }
      __builtin_amdgcn_s_setprio(0);
      if (c & 1) __syncthreads();
    }
  }
  #undef STAGE_K
  #undef STAGE_V
  // write partials (unnormalized O in bf16, running m and l)
  int part = jh * 2 + b;
  unsigned short* ob = opart + ((size_t)part * HW_ + m0) * 512;
  #pragma unroll
  for (int dc = 0; dc < 4; ++dc) {
    int d = dc * 128 + dg * 32 + l31;
    #pragma unroll
    for (int r16 = 0; r16 < 16; ++r16) {
      int row = rw2 * 32 + (r16 & 3) + 8 * (r16 >> 2) + 4 * hl;
      ob[(size_t)row * 512 + d] = f2bf(acc_o[dc][r16]);
    }
  }
  if (t < 64) {
    mpart[(size_t)part * HW_ + m0 + t] = sm_m[t];
    lpart[(size_t)part * HW_ + m0 + t] = sm_l[t];
  }
}

extern "C" void kernel_launch(void* const* d_in, const int* in_sizes, int n_in,
                              void* d_out, int out_size, void* d_ws, size_t ws_size,
                              hipStream_t stream) {
  const float* x     = (const float*)d_in[0];
  const float* gamma = (const float*)d_in[1];
  const float* beta  = (const float*)d_in[2];
  const float* wq    = (const float*)d_in[3];
  const float* bq    = (const float*)d_in[4];
  const float* wk    = (const float*)d_in[5];
  const float* bk    = (const float*)d_in[6];
  const float* wv    = (const float*)d_in[7];
  const float* bv    = (const float*)d_in[8];
  const float* wp    = (const float*)d_in[9];
  const float* bp    = (const float*)d_in[10];
  float* out = (float*)d_out;

  char* ws = (char*)d_ws;
  size_t o = 0;
  float* pstats         = (float*)(ws + o);          o += 32768;     // 8192 f32 partials
  float* biasb          = (float*)(ws + o);          o += 16384;     // 3*2*512 folded biases
  unsigned short* tb    = (unsigned short*)(ws + o); o += 8388608;   // t_raw (b,n,c) bf16
  unsigned short* qb    = (unsigned short*)(ws + o); o += 8388608;
  unsigned short* kb    = (unsigned short*)(ws + o); o += 8388608;
  unsigned short* vTb   = (unsigned short*)(ws + o); o += 8388608;
  unsigned short* wqkvb = (unsigned short*)(ws + o); o += 4194304;   // 8 slots of 512KB (6 used +wp)
  unsigned short* opart = (unsigned short*)(ws + o); o += 16777216;  // 4 parts bf16
  float* mpart          = (float*)(ws + o);          o += 65536;
  float* lpart          = (float*)(ws + o);          o += 65536;

  // single pass over x: transpose/cast + GN partial sums
  sum_t<<<dim3(64, 8, 2), 256, 0, stream>>>(x, pstats, tb);
  // finalize stats; GN folded into per-batch weights + biases; wp cast
  wprep<<<dim3(8, 4, 2), 256, 0, stream>>>(pstats, gamma, beta, wq, wk, wv, wp,
                                           bq, bk, bv, wqkvb, biasb);
  // fused q,k,vT projections (XCD-grouped)
  gemm_qkv<<<dim3(4, 32, 6), 256, 0, stream>>>(tb, wqkvb, biasb, qb, kb, vTb);
  attn<<<dim3(64, 2, 2), 512, 0, stream>>>(qb, kb, vTb, opart, mpart, lpart);
  // final projection with fused partial-merge + residual (512 blocks -> 2/CU)
  gemm_fin<<<dim3(64, 4, 2), 256, 0, stream>>>(wqkvb + (size_t)6 * 262144, opart,
                                               mpart, lpart, bp, x, out);
}

// Round 12
// 260.823 us; speedup vs baseline: 1.0047x; 1.0047x over previous
//
#include <hip/hip_runtime.h>
#include <hip/hip_bf16.h>

#define B_ 2
#define C_ 512
#define HW_ 4096
#define K_ 512
#define EPS_ 1e-6f
#define SCALE_ 0.04419417382415922f   // 512^-0.5
#define NEG_INF_ (-1e30f)

typedef __attribute__((ext_vector_type(8))) __bf16 bf16x8;
typedef __attribute__((ext_vector_type(4))) float f32x4;
typedef __attribute__((ext_vector_type(16))) float f32x16;

__device__ __forceinline__ unsigned short f2bf(float f) {
  union { float f; unsigned u; } v; v.f = f;
  unsigned r = v.u + 0x7fffu + ((v.u >> 16) & 1u);
  return (unsigned short)(r >> 16);
}
__device__ __forceinline__ float bf2f(unsigned short h) {
  union { unsigned u; float f; } v; v.u = ((unsigned)h) << 16;
  return v.f;
}

// direct global->LDS DMA, 16B per lane. LDS dst = wave-uniform base + lane*16.
__device__ __forceinline__ void gld_lds16(const unsigned short* g, unsigned short* l) {
  __builtin_amdgcn_global_load_lds((const __attribute__((address_space(1))) void*)g,
                                   (__attribute__((address_space(3))) void*)l, 16, 0, 0);
}

// ------- sum_t: ONE pass over x. transpose/cast x(b,c,n) f32 -> t_raw(b,n,c) bf16
// AND emit per-block GN partial sums (GN itself is folded into weights by wprep).
// pstats[((b*8+cb)*4+g)*64 + nblk] = sum; +4096 = sumsq.
__global__ void sum_t(const float* __restrict__ x, float* __restrict__ pstats,
                      unsigned short* __restrict__ tb) {
  __shared__ float lds[64 * 69];
  __shared__ float ps[64], ps2[64];
  int n0 = blockIdx.x * 64, c0 = blockIdx.y * 64, b = blockIdx.z;
  int t = threadIdx.x;
  {
    int cl = t >> 2, ch = t & 3;
    const float* xr = x + ((size_t)(b * C_ + c0 + cl)) * HW_ + n0 + ch * 16;
    float s = 0.f, s2 = 0.f;
    #pragma unroll
    for (int i = 0; i < 4; ++i) {
      float4 v = *reinterpret_cast<const float4*>(xr + i * 4);
      int nl = ch * 16 + i * 4;
      lds[cl * 69 + nl + 0] = v.x;
      lds[cl * 69 + nl + 1] = v.y;
      lds[cl * 69 + nl + 2] = v.z;
      lds[cl * 69 + nl + 3] = v.w;
      s  += v.x + v.y + v.z + v.w;
      s2 += v.x * v.x + v.y * v.y + v.z * v.z + v.w * v.w;
    }
    // combine the 4 ch-threads sharing one c (lane bits 0,1)
    s += __shfl_xor(s, 1); s2 += __shfl_xor(s2, 1);
    s += __shfl_xor(s, 2); s2 += __shfl_xor(s2, 2);
    if (ch == 0) { ps[cl] = s; ps2[cl] = s2; }
  }
  __syncthreads();
  if (t < 4) {   // per-group (16 c) partials
    float a = 0.f, a2 = 0.f;
    #pragma unroll
    for (int k = 0; k < 16; ++k) { a += ps[t * 16 + k]; a2 += ps2[t * 16 + k]; }
    int idx = ((b * 8 + blockIdx.y) * 4 + t) * 64 + blockIdx.x;
    pstats[idx] = a; pstats[4096 + idx] = a2;
  }
  {
    int nl = t >> 2, cw = t & 3;
    unsigned short* orow = tb + ((size_t)(b * HW_ + n0 + nl)) * C_ + c0 + cw * 16;
    #pragma unroll
    for (int i = 0; i < 4; ++i) {
      ushort4 o4;
      o4.x = f2bf(lds[(cw * 16 + i * 4 + 0) * 69 + nl]);
      o4.y = f2bf(lds[(cw * 16 + i * 4 + 1) * 69 + nl]);
      o4.z = f2bf(lds[(cw * 16 + i * 4 + 2) * 69 + nl]);
      o4.w = f2bf(lds[(cw * 16 + i * 4 + 3) * 69 + nl]);
      *reinterpret_cast<ushort4*>(orow + i * 4) = o4;
    }
  }
}

// ------- wprep: finalize stats; emit per-batch GN-scaled weights w' = w .* ga (bf16),
// folded biases bias' = b_w + w . be, and the plain wp cast (slot 6).
// grid (8, 4, 2): x = o-block(64), y = which (0=q,1=k,2=v,3=wp), z = b.
// r19: stats reduce PARALLELIZED (r18's 64-iter serial-load loop on 64 threads was a
// ~15-20us latency-bound serial graph node; now 4 threads x 4 float4 per (hf,g) pair).
__global__ void wprep(const float* __restrict__ pstats,
                      const float* __restrict__ gamma, const float* __restrict__ beta,
                      const float* __restrict__ wq, const float* __restrict__ wk,
                      const float* __restrict__ wv, const float* __restrict__ wp,
                      const float* __restrict__ bq, const float* __restrict__ bk,
                      const float* __restrict__ bv,
                      unsigned short* __restrict__ wqkvb, float* __restrict__ biasb) {
  int which = blockIdx.y, b = blockIdx.z;
  if (which == 3 && b == 1) return;
  int t = threadIdx.x;
  __shared__ float sg[32], sg2[32], ga[512], be[512];
  if (which < 3) {
    {
      // 256 threads cover 64 (hf,g) pairs x 4 subs; each sub reads 16 f32 via 4x float4
      int p = t >> 2, sub = t & 3;
      int g = p & 31, hf = p >> 5;
      const float* base = pstats + hf * 4096 + (size_t)(b * 32 + g) * 64 + sub * 16;
      float4 a0 = *reinterpret_cast<const float4*>(base + 0);
      float4 a1 = *reinterpret_cast<const float4*>(base + 4);
      float4 a2 = *reinterpret_cast<const float4*>(base + 8);
      float4 a3 = *reinterpret_cast<const float4*>(base + 12);
      float a = (a0.x + a0.y + a0.z + a0.w) + (a1.x + a1.y + a1.z + a1.w)
              + (a2.x + a2.y + a2.z + a2.w) + (a3.x + a3.y + a3.z + a3.w);
      a += __shfl_xor(a, 1);
      a += __shfl_xor(a, 2);
      if (sub == 0) { if (hf) sg2[g] = a; else sg[g] = a; }
    }
    __syncthreads();
    for (int c = t; c < 512; c += 256) {
      int g = c >> 4;
      float mean = sg[g] * (1.f / 65536.f);
      float var = sg2[g] * (1.f / 65536.f) - mean * mean;
      float rstd = rsqrtf(var + EPS_);
      float gav = gamma[c] * rstd;
      ga[c] = gav; be[c] = beta[c] - mean * gav;
    }
    __syncthreads();
  }
  const float* w = which == 0 ? wq : which == 1 ? wk : which == 2 ? wv : wp;
  int ol = t >> 2, ch = t & 3;
  int o = blockIdx.x * 64 + ol;
  const float* wr = w + (size_t)o * 512 + ch * 128;
  unsigned short* wo = wqkvb + (size_t)(which < 3 ? (which * 2 + b) : 6) * 262144
                     + (size_t)o * 512 + ch * 128;
  float pd = 0.f;
  #pragma unroll 8
  for (int i = 0; i < 32; ++i) {
    float4 v = *reinterpret_cast<const float4*>(wr + i * 4);
    int c = ch * 128 + i * 4;
    ushort4 o4;
    if (which < 3) {
      pd += be[c] * v.x + be[c + 1] * v.y + be[c + 2] * v.z + be[c + 3] * v.w;
      o4.x = f2bf(v.x * ga[c]);     o4.y = f2bf(v.y * ga[c + 1]);
      o4.z = f2bf(v.z * ga[c + 2]); o4.w = f2bf(v.w * ga[c + 3]);
    } else {
      o4.x = f2bf(v.x); o4.y = f2bf(v.y); o4.z = f2bf(v.z); o4.w = f2bf(v.w);
    }
    *reinterpret_cast<ushort4*>(wo + i * 4) = o4;
  }
  if (which < 3) {
    pd += __shfl_xor(pd, 1);
    pd += __shfl_xor(pd, 2);
    if (ch == 0) {
      const float* b0 = which == 0 ? bq : which == 1 ? bk : bv;
      biasb[(which * 2 + b) * 512 + o] = b0[o] + pd;
    }
  }
}

// ---------------- fused Q/K/V^T projections, one launch (XCD-grouped) ----------------
// per-batch scaled weights from wprep; folded biases from biasb.
__global__ __launch_bounds__(256, 2) void gemm_qkv(
    const unsigned short* __restrict__ tb, const unsigned short* __restrict__ wqkvb,
    const float* __restrict__ biasb,
    unsigned short* __restrict__ qb, unsigned short* __restrict__ kb,
    unsigned short* __restrict__ vTb) {
  __shared__ unsigned short Al[2][128 * 64];
  __shared__ unsigned short Bl[2][128 * 64];
  // bijective remap of 768 blocks: xcd = f&7 fixed; i>>2 selects (y,z) combo, i&3 the x
  int f = blockIdx.x + 4 * (blockIdx.y + 32 * blockIdx.z);
  int xcd = f & 7, i = f >> 3;
  int bx = i & 3;
  int g = xcd * 24 + (i >> 2);     // 0..191
  int bz = g >> 5, by = g & 31;
  int which = bz >> 1, b = bz & 1;
  const unsigned short* Ab = (which < 2) ? (tb + (size_t)b * HW_ * K_)
                                         : (wqkvb + (size_t)(4 + b) * 262144);
  const unsigned short* Bb = (which < 2) ? (wqkvb + (size_t)(which * 2 + b) * 262144)
                                         : (tb + (size_t)b * HW_ * K_);
  int m0 = (which < 2) ? by * 128 : bx * 128;
  int n0 = (which < 2) ? bx * 128 : by * 128;
  int N = (which < 2) ? 512 : HW_;
  unsigned short* Cb = (which == 0) ? (qb + (size_t)b * HW_ * K_)
                     : (which == 1) ? (kb + (size_t)b * HW_ * K_)
                                    : (vTb + (size_t)b * C_ * HW_);
  const float* bias = biasb + (which * 2 + b) * 512;
  int t = threadIdx.x, lane = t & 63, w = t >> 6;
  int l15 = lane & 15, quad = lane >> 4;
  int mw = (w & 1) * 64, nw = (w >> 1) * 64;
  int sr8 = lane >> 3, sb = lane & 7;
  f32x4 acc[4][4] = {};

  #define G_STAGE(KC) do {                                                          \
    int pb = (KC) & 1;                                                              \
    _Pragma("unroll")                                                               \
    for (int q = 0; q < 4; ++q) {                                                   \
      int row = w * 32 + q * 8 + sr8;                                               \
      int gb = sb ^ (row & 7);                                                      \
      gld_lds16(Ab + (size_t)(m0 + row) * K_ + (KC) * 64 + gb * 8, &Al[pb][(w * 32 + q * 8) * 64]); \
      gld_lds16(Bb + (size_t)(n0 + row) * K_ + (KC) * 64 + gb * 8, &Bl[pb][(w * 32 + q * 8) * 64]); \
    }                                                                               \
  } while (0)

  G_STAGE(0);
  __syncthreads();
  for (int kc = 0; kc < 8; ++kc) {
    if (kc < 7) G_STAGE(kc + 1);
    const unsigned short* Ac = Al[kc & 1];
    const unsigned short* Bc = Bl[kc & 1];
    #pragma unroll
    for (int kk = 0; kk < 2; ++kk) {
      bf16x8 af[4];
      #pragma unroll
      for (int mt = 0; mt < 4; ++mt)
        af[mt] = *reinterpret_cast<const bf16x8*>(
            &Ac[(mw + mt * 16 + l15) * 64 + (((kk * 4 + quad) ^ (l15 & 7)) << 3)]);
      #pragma unroll
      for (int nt = 0; nt < 4; ++nt) {
        bf16x8 bfr = *reinterpret_cast<const bf16x8*>(
            &Bc[(nw + nt * 16 + l15) * 64 + (((kk * 4 + quad) ^ (l15 & 7)) << 3)]);
        #pragma unroll
        for (int mt = 0; mt < 4; ++mt)
          acc[mt][nt] = __builtin_amdgcn_mfma_f32_16x16x32_bf16(af[mt], bfr, acc[mt][nt], 0, 0, 0);
      }
    }
    __syncthreads();
  }
  #undef G_STAGE
  #pragma unroll
  for (int mt = 0; mt < 4; ++mt)
    #pragma unroll
    for (int nt = 0; nt < 4; ++nt)
      #pragma unroll
      for (int rr = 0; rr < 4; ++rr) {
        int row = m0 + mw + mt * 16 + quad * 4 + rr;
        int col = n0 + nw + nt * 16 + l15;
        float v = acc[mt][nt][rr] + ((which < 2) ? bias[col] : bias[row]);
        Cb[(size_t)row * N + col] = f2bf(v);
      }
}

// ---------------- final projection + residual, with fused opart merge ----------------
// 128x64 tiles -> 512 blocks -> 2 blocks/CU co-resident (r16-verified).
__global__ __launch_bounds__(256, 2) void gemm_fin(
    const unsigned short* __restrict__ A,            // wpb 512x512 bf16 (slot 6)
    const unsigned short* __restrict__ opart,        // 4 parts (jh*2+z)
    const float* __restrict__ mpart, const float* __restrict__ lpart,
    const float* __restrict__ bias, const float* __restrict__ resid,
    float* __restrict__ out) {
  __shared__ unsigned short Al[2][128 * 64];
  __shared__ unsigned short Bl[2][64 * 68];    // padded: row stride 68 shorts
  int z = blockIdx.z;
  int n0 = blockIdx.x * 64, m0 = blockIdx.y * 128;
  int t = threadIdx.x, lane = t & 63, w = t >> 6;
  int l15 = lane & 15, quad = lane >> 4;
  int mw = (w & 1) * 64, nw = (w >> 1) * 32;   // 2 m-waves(64) x 2 n-waves(32)
  int sr8 = lane >> 3, sb = lane & 7;
  f32x4 acc[4][2] = {};

  float w0[2], w1[2];
  int nrow[2];
  #pragma unroll
  for (int q = 0; q < 2; ++q) {
    int n = n0 + w * 16 + q * 8 + sr8;
    nrow[q] = n;
    float ma = mpart[(size_t)z * HW_ + n], mb = mpart[(size_t)(2 + z) * HW_ + n];
    float la = lpart[(size_t)z * HW_ + n], lb = lpart[(size_t)(2 + z) * HW_ + n];
    float M = fmaxf(ma, mb);
    float ea = __expf(ma - M), eb = __expf(mb - M);
    float iv = 1.f / (la * ea + lb * eb);
    w0[q] = ea * iv; w1[q] = eb * iv;
  }
  const unsigned short* p0 = opart + (size_t)z * HW_ * 512;
  const unsigned short* p1 = opart + (size_t)(2 + z) * HW_ * 512;

  #define STAGE_A(KC) do {                                                          \
    int pb = (KC) & 1;                                                              \
    _Pragma("unroll")                                                               \
    for (int q = 0; q < 4; ++q) {                                                   \
      int row = w * 32 + q * 8 + sr8;                                               \
      int gb = sb ^ (row & 7);                                                      \
      gld_lds16(A + (size_t)(m0 + row) * K_ + (KC) * 64 + gb * 8, &Al[pb][(w * 32 + q * 8) * 64]); \
    }                                                                               \
  } while (0)

  #define STAGE_B(KC) do {                                                          \
    int pb = (KC) & 1;                                                              \
    _Pragma("unroll")                                                               \
    for (int q = 0; q < 2; ++q) {                                                   \
      int row = w * 16 + q * 8 + sr8;                                               \
      size_t goff = (size_t)nrow[q] * 512 + (KC) * 64 + sb * 8;                     \
      uint4 u0 = *reinterpret_cast<const uint4*>(p0 + goff);                        \
      uint4 u1 = *reinterpret_cast<const uint4*>(p1 + goff);                        \
      uint4 o4;                                                                     \
      unsigned* a0 = reinterpret_cast<unsigned*>(&u0);                              \
      unsigned* a1 = reinterpret_cast<unsigned*>(&u1);                              \
      unsigned* od = reinterpret_cast<unsigned*>(&o4);                              \
      _Pragma("unroll")                                                             \
      for (int j = 0; j < 4; ++j) {                                                 \
        float lo = bf2f((unsigned short)(a0[j] & 0xffffu)) * w0[q]                  \
                 + bf2f((unsigned short)(a1[j] & 0xffffu)) * w1[q];                 \
        float hi = bf2f((unsigned short)(a0[j] >> 16)) * w0[q]                      \
                 + bf2f((unsigned short)(a1[j] >> 16)) * w1[q];                     \
        od[j] = (unsigned)f2bf(lo) | ((unsigned)f2bf(hi) << 16);                    \
      }                                                                             \
      *reinterpret_cast<uint4*>(&Bl[pb][row * 68 + sb * 8]) = o4;                   \
    }                                                                               \
  } while (0)

  STAGE_A(0);
  STAGE_B(0);
  __syncthreads();
  for (int kc = 0; kc < 8; ++kc) {
    if (kc < 7) { STAGE_A(kc + 1); STAGE_B(kc + 1); }
    const unsigned short* Ac = Al[kc & 1];
    const unsigned short* Bc = Bl[kc & 1];
    #pragma unroll
    for (int kk = 0; kk < 2; ++kk) {
      bf16x8 af[4];
      #pragma unroll
      for (int mt = 0; mt < 4; ++mt)
        af[mt] = *reinterpret_cast<const bf16x8*>(
            &Ac[(mw + mt * 16 + l15) * 64 + (((kk * 4 + quad) ^ (l15 & 7)) << 3)]);
      #pragma unroll
      for (int nt = 0; nt < 2; ++nt) {
        bf16x8 bfr = *reinterpret_cast<const bf16x8*>(
            &Bc[(nw + nt * 16 + l15) * 68 + ((kk * 4 + quad) << 3)]);
        #pragma unroll
        for (int mt = 0; mt < 4; ++mt)
          acc[mt][nt] = __builtin_amdgcn_mfma_f32_16x16x32_bf16(af[mt], bfr, acc[mt][nt], 0, 0, 0);
      }
    }
    __syncthreads();
  }
  #undef STAGE_A
  #undef STAGE_B
  #pragma unroll
  for (int mt = 0; mt < 4; ++mt)
    #pragma unroll
    for (int nt = 0; nt < 2; ++nt)
      #pragma unroll
      for (int rr = 0; rr < 4; ++rr) {
        int row = m0 + mw + mt * 16 + quad * 4 + rr;
        int col = n0 + nw + nt * 16 + l15;
        size_t idx = (size_t)z * (C_ * HW_) + (size_t)row * HW_ + col;
        out[idx] = acc[mt][nt][rr] + bias[row] + resid[idx];
      }
}

// ------- flash attention r17 (verified 132 us): phase-PAIRED, 2 chunks per barrier,
// 4 rotating 32KB buffers; 11 barriers/it; Pl single 128-col half rewritten mid-PV.
__global__ __launch_bounds__(512, 2) void attn(
    const unsigned short* __restrict__ qg, const unsigned short* __restrict__ kg,
    const unsigned short* __restrict__ vg,  // vT: (b, c, n)
    unsigned short* __restrict__ opart, float* __restrict__ mpart, float* __restrict__ lpart) {
  __shared__ unsigned short KVb[4 * 16384];   // 4 x 32KB rotating chunk buffers
  __shared__ unsigned short Pl[64 * 136];     // one 128-j half + pad, 17408 B
  __shared__ float sm_m[64], sm_l[64], sm_alpha[64], sm_red[128];
  int qt = blockIdx.x, jh = blockIdx.y, b = blockIdx.z;
  int t = threadIdx.x, lane = t & 63, w = t >> 6;
  int l15 = lane & 15, quad = lane >> 4;
  int l31 = lane & 31, hl = lane >> 5;
  int rw = w & 3, cw = w >> 2;      // S phase: 4 row-groups(16) x 2 col-halves
  int rw2 = w & 1, dg = w >> 1;     // PV phase: 2 row-groups(32) x 4 d-slots
  int m0 = qt * 64;
  if (t < 64) { sm_m[t] = NEG_INF_; sm_l[t] = 0.f; }

  // staging geometry: thread stages 4 x 16B; wave w covers 1KB blocks w*4+q (4 rows each)
  int st_r[4], st_kb[4];
  #pragma unroll
  for (int q = 0; q < 4; ++q) {
    int blk = w * 4 + q;
    st_r[q] = blk * 4 + (lane >> 4);          // row 0..127 within chunk
    st_kb[q] = (lane & 15) ^ (st_r[q] & 7);   // logical 16B block (col/8)
  }

  #define STAGE_K(JC, KC, J0, BUF) do {                                             \
    const unsigned short* gb = kg + ((size_t)(b * HW_ + (J0) + (JC) * 128)) * K_ + (KC) * 128; \
    unsigned short* lb = KVb + ((BUF) << 14);                                       \
    _Pragma("unroll")                                                               \
    for (int q = 0; q < 4; ++q)                                                     \
      gld_lds16(gb + (size_t)st_r[q] * K_ + st_kb[q] * 8, lb + (w * 4 + q) * 512);  \
  } while (0)

  #define STAGE_V(DC, JC, J0, BUF) do {                                             \
    const unsigned short* gb = vg + ((size_t)(b * K_ + (DC) * 128)) * HW_ + (J0) + (JC) * 128; \
    unsigned short* lb = KVb + ((BUF) << 14);                                       \
    _Pragma("unroll")                                                               \
    for (int q = 0; q < 4; ++q)                                                     \
      gld_lds16(gb + (size_t)st_r[q] * HW_ + st_kb[q] * 8, lb + (w * 4 + q) * 512); \
  } while (0)

  bf16x8 qa[16];
  {
    const unsigned short* qrow = qg + ((size_t)(b * HW_ + m0 + rw * 16 + l15)) * K_ + quad * 8;
    #pragma unroll
    for (int kk = 0; kk < 16; ++kk)
      qa[kk] = *reinterpret_cast<const bf16x8*>(qrow + kk * 32);
  }
  f32x16 acc_o[4] = {};    // [dc]: d = dc*128 + dg*32 + l31

  int j0 = jh * 2048;
  STAGE_K(0, 0, j0, 0);    // S chunk 0 -> buf 0
  STAGE_K(0, 1, j0, 1);    // S chunk 1 -> buf 1
  __syncthreads();         // drains chunks 0,1; publishes sm init

  for (int it = 0; it < 8; ++it, j0 += 256) {
    f32x4 acc_s[8] = {};
    // ===== S: 8 chunks (jc=c>>2, kc=c&3), chunk c in buf c&3; barrier at odd c =====
    #pragma unroll
    for (int c = 0; c < 8; ++c) {
      if ((c & 1) == 0) {
        if (c < 6) {
          STAGE_K((c + 2) >> 2, (c + 2) & 3, j0, (c + 2) & 3);
          STAGE_K((c + 3) >> 2, (c + 3) & 3, j0, (c + 3) & 3);
        } else {           // c==6: stage PV chunks 0,1 (V dc=0,1 jc=0) -> bufs 0,1
          STAGE_V(0, 0, j0, 0);
          STAGE_V(1, 0, j0, 1);
        }
      }
      const unsigned short* bufc = KVb + ((c & 3) << 14);
      int jc = c >> 2, kc = c & 3;
      __builtin_amdgcn_s_setprio(1);
      #pragma unroll
      for (int kk = 0; kk < 4; ++kk)
        #pragma unroll
        for (int ct = 0; ct < 4; ++ct) {
          int jr = cw * 64 + ct * 16 + l15;
          bf16x8 bfr = *reinterpret_cast<const bf16x8*>(
              &bufc[jr * 128 + (((kk * 4 + quad) ^ (l15 & 7)) << 3)]);
          acc_s[jc * 4 + ct] = __builtin_amdgcn_mfma_f32_16x16x32_bf16(qa[kc * 4 + kk], bfr, acc_s[jc * 4 + ct], 0, 0, 0);
        }
      __builtin_amdgcn_s_setprio(0);
      if (c & 1) __syncthreads();
    }
    // ===== softmax =====
    float mx[4];
    #pragma unroll
    for (int rr = 0; rr < 4; ++rr) {
      float m = NEG_INF_;
      #pragma unroll
      for (int s = 0; s < 8; ++s) {
        acc_s[s][rr] *= SCALE_;
        m = fmaxf(m, acc_s[s][rr]);
      }
      mx[rr] = m;
    }
    #pragma unroll
    for (int off = 1; off < 16; off <<= 1)
      #pragma unroll
      for (int rr = 0; rr < 4; ++rr)
        mx[rr] = fmaxf(mx[rr], __shfl_xor(mx[rr], off));
    if (l15 == 0)
      #pragma unroll
      for (int rr = 0; rr < 4; ++rr)
        sm_red[cw * 64 + rw * 16 + quad * 4 + rr] = mx[rr];
    __syncthreads();
    if (t < 64) {
      float mnew = fmaxf(sm_m[t], fmaxf(sm_red[t], sm_red[64 + t]));
      sm_alpha[t] = __expf(sm_m[t] - mnew);
      sm_m[t] = mnew;
    }
    __syncthreads();
    float sum[4] = {0.f, 0.f, 0.f, 0.f};
    #pragma unroll
    for (int s = 0; s < 8; ++s)
      #pragma unroll
      for (int rr = 0; rr < 4; ++rr) {
        int rowl = rw * 16 + quad * 4 + rr;
        float p = __expf(acc_s[s][rr] - sm_m[rowl]);
        sum[rr] += p;
        if (s < 4)   // jc=0 half only; jc=1 rewritten mid-PV from acc_s[4..7]
          Pl[rowl * 136 + cw * 64 + (s & 3) * 16 + l15] = f2bf(p);
      }
    #pragma unroll
    for (int off = 1; off < 16; off <<= 1)
      #pragma unroll
      for (int rr = 0; rr < 4; ++rr)
        sum[rr] += __shfl_xor(sum[rr], off);
    if (l15 == 0)
      #pragma unroll
      for (int rr = 0; rr < 4; ++rr)
        sm_red[cw * 64 + rw * 16 + quad * 4 + rr] = sum[rr];
    __syncthreads();
    if (t < 64)
      sm_l[t] = sm_l[t] * sm_alpha[t] + sm_red[t] + sm_red[64 + t];
    // rescale O by alpha (32x32 C/D row mapping)
    #pragma unroll
    for (int r16 = 0; r16 < 16; ++r16) {
      int row = rw2 * 32 + (r16 & 3) + 8 * (r16 >> 2) + 4 * hl;
      float a = sm_alpha[row];
      #pragma unroll
      for (int dc = 0; dc < 4; ++dc)
        acc_o[dc][r16] *= a;
    }
    // ===== PV: 8 chunks (jc=c>>2, dc=c&3), global 8+c -> buf c&3; barrier at odd c =====
    bf16x8 pa_r[8];
    #pragma unroll
    for (int c = 0; c < 8; ++c) {
      if (c == 2) {
        // rewrite Pl with jc=1 half (jc0 reads done: pa_r loaded at c=0, barrier c=1;
        // reads of this data at c=4, after barrier c=3)
        #pragma unroll
        for (int s = 4; s < 8; ++s)
          #pragma unroll
          for (int rr = 0; rr < 4; ++rr) {
            int rowl = rw * 16 + quad * 4 + rr;
            Pl[rowl * 136 + cw * 64 + (s & 3) * 16 + l15] =
                f2bf(__expf(acc_s[s][rr] - sm_m[rowl]));
          }
      }
      if ((c & 3) == 0) {
        #pragma unroll
        for (int ksx = 0; ksx < 8; ++ksx)
          pa_r[ksx] = *reinterpret_cast<const bf16x8*>(
              &Pl[(rw2 * 32 + l31) * 136 + ksx * 16 + hl * 8]);
      }
      if ((c & 1) == 0) {
        if (c < 6) {
          STAGE_V((c + 2) & 3, (c + 2) >> 2, j0, (c + 2) & 3);
          STAGE_V((c + 3) & 3, (c + 3) >> 2, j0, (c + 3) & 3);
        } else if (it < 7) {   // c==6: stage next-it S chunks 0,1 -> bufs 0,1
          STAGE_K(0, 0, j0 + 256, 0);
          STAGE_K(0, 1, j0 + 256, 1);
        }
      }
      const unsigned short* bufc = KVb + ((c & 3) << 14);
      int dc = c & 3;
      __builtin_amdgcn_s_setprio(1);
      #pragma unroll
      for (int ksx = 0; ksx < 8; ++ksx) {
        bf16x8 vb = *reinterpret_cast<const bf16x8*>(
            &bufc[(dg * 32 + l31) * 128 + (((ksx * 2 + hl) ^ (l31 & 7)) << 3)]);
        acc_o[dc] = __builtin_amdgcn_mfma_f32_32x32x16_bf16(pa_r[ksx], vb, acc_o[dc], 0, 0, 0);
      }
      __builtin_amdgcn_s_setprio(0);
      if (c & 1) __syncthreads();
    }
  }
  #undef STAGE_K
  #undef STAGE_V
  // write partials (unnormalized O in bf16, running m and l)
  int part = jh * 2 + b;
  unsigned short* ob = opart + ((size_t)part * HW_ + m0) * 512;
  #pragma unroll
  for (int dc = 0; dc < 4; ++dc) {
    int d = dc * 128 + dg * 32 + l31;
    #pragma unroll
    for (int r16 = 0; r16 < 16; ++r16) {
      int row = rw2 * 32 + (r16 & 3) + 8 * (r16 >> 2) + 4 * hl;
      ob[(size_t)row * 512 + d] = f2bf(acc_o[dc][r16]);
    }
  }
  if (t < 64) {
    mpart[(size_t)part * HW_ + m0 + t] = sm_m[t];
    lpart[(size_t)part * HW_ + m0 + t] = sm_l[t];
  }
}

extern "C" void kernel_launch(void* const* d_in, const int* in_sizes, int n_in,
                              void* d_out, int out_size, void* d_ws, size_t ws_size,
                              hipStream_t stream) {
  const float* x     = (const float*)d_in[0];
  const float* gamma = (const float*)d_in[1];
  const float* beta  = (const float*)d_in[2];
  const float* wq    = (const float*)d_in[3];
  const float* bq    = (const float*)d_in[4];
  const float* wk    = (const float*)d_in[5];
  const float* bk    = (const float*)d_in[6];
  const float* wv    = (const float*)d_in[7];
  const float* bv    = (const float*)d_in[8];
  const float* wp    = (const float*)d_in[9];
  const float* bp    = (const float*)d_in[10];
  float* out = (float*)d_out;

  char* ws = (char*)d_ws;
  size_t o = 0;
  float* pstats         = (float*)(ws + o);          o += 32768;     // 8192 f32 partials
  float* biasb          = (float*)(ws + o);          o += 16384;     // 3*2*512 folded biases
  unsigned short* tb    = (unsigned short*)(ws + o); o += 8388608;   // t_raw (b,n,c) bf16
  unsigned short* qb    = (unsigned short*)(ws + o); o += 8388608;
  unsigned short* kb    = (unsigned short*)(ws + o); o += 8388608;
  unsigned short* vTb   = (unsigned short*)(ws + o); o += 8388608;
  unsigned short* wqkvb = (unsigned short*)(ws + o); o += 4194304;   // 8 slots of 512KB (6 used +wp)
  unsigned short* opart = (unsigned short*)(ws + o); o += 16777216;  // 4 parts bf16
  float* mpart          = (float*)(ws + o);          o += 65536;
  float* lpart          = (float*)(ws + o);          o += 65536;

  // single pass over x: transpose/cast + GN partial sums
  sum_t<<<dim3(64, 8, 2), 256, 0, stream>>>(x, pstats, tb);
  // finalize stats; GN folded into per-batch weights + biases; wp cast (parallel reduce)
  wprep<<<dim3(8, 4, 2), 256, 0, stream>>>(pstats, gamma, beta, wq, wk, wv, wp,
                                           bq, bk, bv, wqkvb, biasb);
  // fused q,k,vT projections (XCD-grouped)
  gemm_qkv<<<dim3(4, 32, 6), 256, 0, stream>>>(tb, wqkvb, biasb, qb, kb, vTb);
  attn<<<dim3(64, 2, 2), 512, 0, stream>>>(qb, kb, vTb, opart, mpart, lpart);
  // final projection with fused partial-merge + residual (512 blocks -> 2/CU)
  gemm_fin<<<dim3(64, 4, 2), 256, 0, stream>>>(wqkvb + (size_t)6 * 262144, opart,
                                               mpart, lpart, bp, x, out);
}